// Round 7
// baseline (2155.962 us; speedup 1.0000x reference)
//
#include <hip/hip_runtime.h>
#include <stdint.h>

// ===================== Round 7 =====================
// R6 schedule (16 chunks, ring-4, counted vmcnt(2), pipelined GEMM2
// one chunk behind, per-chunk s_barrier, setprio) with both GEMMs
// switched to v_mfma_f32_32x32x16_f16:
//  - per-MAC 4.85 -> 4.03 cyc (MFMA floor 663 -> 551us)
//  - MFMA inst count halved -> less loop/VALU overhead
//  - wave's batch-32 = one 32-wide N-tile; state regs unchanged.
// C/D: col=lane&31, row=(reg&3)+8*(reg>>2)+4*(lane>>5) [m74/m101].
// A/B: m(n)=lane&31, k=(lane>>5)*8+j.
// Predict: 1800-1950us, absmax ~0.031, VALU 19-22, conflicts 4-6e7.
// ===================================================

typedef _Float16 half8 __attribute__((ext_vector_type(8)));
typedef float f32x4 __attribute__((ext_vector_type(4)));
typedef float f32x16 __attribute__((ext_vector_type(16)));
typedef __attribute__((address_space(3))) char lchar;
typedef __attribute__((address_space(1))) char gchar;

#define XSTR 136  // shorts per xs row (128 + 8 pad), 272B, rows 16B-aligned
#define HSTR 40   // shorts per hst row (32 + 8 pad), 80B, rows 16B-aligned

static __device__ __forceinline__ void gload_lds16(const void* g, void* l) {
  __builtin_amdgcn_global_load_lds((const gchar*)g, (lchar*)l, 16, 0, 0);
}

static __device__ __forceinline__ unsigned short f2h(float x) {
  union { _Float16 h; unsigned short u; } cv;
  cv.h = (_Float16)x;
  return cv.u;
}
static __device__ __forceinline__ float h2f(unsigned short u) {
  union { unsigned short u; _Float16 h; } cv;
  cv.u = u;
  return (float)cv.h;
}
static __device__ __forceinline__ uint64_t pack4(float a, float b, float c, float d) {
  union { _Float16 h[4]; uint64_t q; } cv;
  cv.h[0] = (_Float16)a; cv.h[1] = (_Float16)b;
  cv.h[2] = (_Float16)c; cv.h[3] = (_Float16)d;
  return cv.q;
}

// Prepack W1^T / W2^T as 32x32x16 A-frag streams.
// A-frag: lane l holds A[m = l&31][k = (l>>5)*8 + j], 8 halves = 16B.
// 16 chunks of 32 hid; chunk c at wp + c*16384 (16 frags x 1KB):
//  f = 0..7   : W1T, ks = f:  m = hid c*32 + (l&31), k_in = ks*16 + (l>>5)*8 + j
//  f = 8..15  : W2T, O = (f-8)>>1, kf = (f-8)&1:
//               m = out O*32 + (l&31), k_hid = c*32 + kf*16 + (l>>5)*8 + j
__global__ void pack_w(const float* __restrict__ W1, const float* __restrict__ W2,
                       unsigned short* __restrict__ wp) {
  int id = blockIdx.x * 256 + threadIdx.x;  // 0..16383
  int lane = id & 63, fid = (id >> 6) & 255;
  int n32 = lane & 31, hi = lane >> 5;
  int c = fid >> 4, f = fid & 15;
  if (f < 8) {
    int hid = c * 32 + n32;
#pragma unroll
    for (int j = 0; j < 8; ++j) {
      int kin = f * 16 + hi * 8 + j;
      wp[fid * 512 + lane * 8 + j] = f2h(W1[kin * 512 + hid]);
    }
  } else {
    int u = f - 8, O = u >> 1, kf = u & 1;
    int of = O * 32 + n32;
#pragma unroll
    for (int j = 0; j < 8; ++j) {
      int kh = c * 32 + kf * 16 + hi * 8 + j;
      wp[fid * 512 + lane * 8 + j] = f2h(W2[kh * 128 + of]);
    }
  }
}

__global__ __launch_bounds__(512, 2) void node_rk4(
    const float* __restrict__ x0, const float* __restrict__ b1,
    const float* __restrict__ b2, const unsigned short* __restrict__ wp,
    float* __restrict__ out) {
  __shared__ char Wbuf[4][16384];
  __shared__ __align__(16) unsigned short xs[8][32][XSTR];   // x_in, fp16
  __shared__ __align__(16) unsigned short hst[8][32][HSTR];  // h chunk, fp16
  __shared__ float b1s[512];
  __shared__ float b2s[128];

  const int tid = threadIdx.x;
  const int w = tid >> 6, lane = tid & 63;
  const int n32 = lane & 31, hi = lane >> 5;

  b1s[tid] = b1[tid];
  if (tid < 128) b2s[tid] = b2[tid];

  // State: lane holds batch col rbase+n32; feature rows O*32 + 8q + 4hi + j.
  const int rbase = blockIdx.x * 256 + w * 32;
  f32x4 xa[4][4];
  ushort4 xbh[4][4];
#pragma unroll
  for (int O = 0; O < 4; ++O)
#pragma unroll
    for (int q = 0; q < 4; ++q) {
      f32x4 v = *(const f32x4*)&x0[(rbase + n32) * 128 + O * 32 + 8 * q + 4 * hi];
      xa[O][q] = v;
      uint64_t qq = pack4(v[0], v[1], v[2], v[3]);
      ushort4 hq;
      *(uint64_t*)&hq = qq;
      xbh[O][q] = hq;
      *(uint64_t*)&xs[w][n32][O * 32 + 8 * q + 4 * hi] = qq;
    }

  // Prologue: prefetch W chunks 0,1 into ring slots 0,1 (depth 2).
#pragma unroll
  for (int pc = 0; pc < 2; ++pc) {
    const char* src = (const char*)wp + pc * 16384;
#pragma unroll
    for (int q = 0; q < 2; ++q) {
      int seg = w * 2 + q;
      gload_lds16(src + seg * 1024 + lane * 16, Wbuf[pc] + seg * 1024);
    }
  }
  asm volatile("s_waitcnt vmcnt(2) lgkmcnt(0)" ::: "memory");
  __builtin_amdgcn_s_barrier();

#pragma unroll 1
  for (int it = 0; it < 80; ++it) {
    const int s = it & 3;
    const float wgt = (s == 0 || s == 3) ? (0.1f / 6.0f) : (0.1f / 3.0f);
    const float alph = (s < 2) ? 0.05f : 0.1f;

    // x^T B-frags (K_in=128 -> 8 frags of K=16), held all eval.
    half8 X1[8];
#pragma unroll
    for (int ks = 0; ks < 8; ++ks)
      X1[ks] = *(const half8*)&xs[w][n32][ks * 16 + hi * 8];

    f32x16 yacc[4];
#pragma unroll
    for (int O = 0; O < 4; ++O)
#pragma unroll
      for (int e = 0; e < 16; ++e) yacc[O][e] = 0.f;

#pragma unroll
    for (int c = 0; c < 16; ++c) {
      // h(c-1) B-frags (written one full chunk ago, wave-private).
      half8 Hp0, Hp1;
      if (c > 0) {
        Hp0 = *(const half8*)&hst[w][n32][hi * 8];
        Hp1 = *(const half8*)&hst[w][n32][16 + hi * 8];
      }

      // Prefetch chunk (c+2)&15 into ring slot (c+2)&3.
      {
        const int cn = (c + 2) & 15;
        char* buf = Wbuf[(c + 2) & 3];
        const char* src = (const char*)wp + cn * 16384;
#pragma unroll
        for (int q = 0; q < 2; ++q) {
          int seg = w * 2 + q;
          gload_lds16(src + seg * 1024 + lane * 16, buf + seg * 1024);
        }
      }

      __builtin_amdgcn_s_setprio(1);
      // GEMM2'(c-1): y^T += W2T(c-1) x h^T(c-1).  4 O-tiles x 2 k-frags.
      if (c > 0) {
        const char* Wp = Wbuf[(c + 3) & 3];  // == (c-1)&3
#pragma unroll
        for (int O = 0; O < 4; ++O) {
          half8 wa0 = *(const half8*)(Wp + 8192 + (O * 2 + 0) * 1024 + lane * 16);
          half8 wa1 = *(const half8*)(Wp + 8192 + (O * 2 + 1) * 1024 + lane * 16);
          yacc[O] = __builtin_amdgcn_mfma_f32_32x32x16_f16(wa0, Hp0, yacc[O], 0, 0, 0);
          yacc[O] = __builtin_amdgcn_mfma_f32_32x32x16_f16(wa1, Hp1, yacc[O], 0, 0, 0);
        }
      }

      // GEMM1'(c): h^T (hid 32 x batch 32) over K_in=128 (8 chained frags).
      const char* Wb = Wbuf[c & 3];
      f32x16 hacc;
#pragma unroll
      for (int e = 0; e < 16; ++e) hacc[e] = 0.f;
#pragma unroll
      for (int ks = 0; ks < 8; ++ks) {
        half8 wa = *(const half8*)(Wb + ks * 1024 + lane * 16);
        hacc = __builtin_amdgcn_mfma_f32_32x32x16_f16(wa, X1[ks], hacc, 0, 0, 0);
      }
      __builtin_amdgcn_s_setprio(0);

      // bias + relu + pack -> hst (feat rows 8q+4hi..+3 for batch col n32).
#pragma unroll
      for (int q = 0; q < 4; ++q) {
        f32x4 bb = *(const f32x4*)&b1s[c * 32 + 8 * q + 4 * hi];
        uint64_t p = pack4(fmaxf(hacc[4 * q + 0] + bb[0], 0.f),
                           fmaxf(hacc[4 * q + 1] + bb[1], 0.f),
                           fmaxf(hacc[4 * q + 2] + bb[2], 0.f),
                           fmaxf(hacc[4 * q + 3] + bb[3], 0.f));
        *(uint64_t*)&hst[w][n32][8 * q + 4 * hi] = p;
      }

      // Counted wait: outstanding {c+1, c+2} x2 loads; ensure c+1 landed.
      asm volatile("s_waitcnt vmcnt(2)" ::: "memory");
      __builtin_amdgcn_s_barrier();
    }

    // Tail GEMM2'(15).
    {
      half8 Hl0 = *(const half8*)&hst[w][n32][hi * 8];
      half8 Hl1 = *(const half8*)&hst[w][n32][16 + hi * 8];
      const char* Wp = Wbuf[3];  // 15 & 3
#pragma unroll
      for (int O = 0; O < 4; ++O) {
        half8 wa0 = *(const half8*)(Wp + 8192 + (O * 2 + 0) * 1024 + lane * 16);
        half8 wa1 = *(const half8*)(Wp + 8192 + (O * 2 + 1) * 1024 + lane * 16);
        yacc[O] = __builtin_amdgcn_mfma_f32_32x32x16_f16(wa0, Hl0, yacc[O], 0, 0, 0);
        yacc[O] = __builtin_amdgcn_mfma_f32_32x32x16_f16(wa1, Hl1, yacc[O], 0, 0, 0);
      }
    }

    // RK4 combine; write next x_in (packed b64) into xs.
#pragma unroll
    for (int O = 0; O < 4; ++O)
#pragma unroll
      for (int q = 0; q < 4; ++q) {
        f32x4 bb2 = *(const f32x4*)&b2s[O * 32 + 8 * q + 4 * hi];
        f32x4 k;
#pragma unroll
        for (int j = 0; j < 4; ++j) k[j] = yacc[O][4 * q + j] + bb2[j];
        xa[O][q] += wgt * k;
        uint64_t qq;
        if (s == 3) {
          f32x4 v = xa[O][q];
          qq = pack4(v[0], v[1], v[2], v[3]);
          ushort4 hq;
          *(uint64_t*)&hq = qq;
          xbh[O][q] = hq;
        } else {
          ushort4 xq = xbh[O][q];
          qq = pack4(h2f(xq.x) + alph * k[0], h2f(xq.y) + alph * k[1],
                     h2f(xq.z) + alph * k[2], h2f(xq.w) + alph * k[3]);
        }
        *(uint64_t*)&xs[w][n32][O * 32 + 8 * q + 4 * hi] = qq;
      }
  }

#pragma unroll
  for (int O = 0; O < 4; ++O)
#pragma unroll
    for (int q = 0; q < 4; ++q)
      *(f32x4*)&out[(rbase + n32) * 128 + O * 32 + 8 * q + 4 * hi] = xa[O][q];
}

extern "C" void kernel_launch(void* const* d_in, const int* in_sizes, int n_in,
                              void* d_out, int out_size, void* d_ws, size_t ws_size,
                              hipStream_t stream) {
  const float* x0 = (const float*)d_in[0];
  const float* W1 = (const float*)d_in[1];
  const float* b1 = (const float*)d_in[2];
  const float* W2 = (const float*)d_in[3];
  const float* b2 = (const float*)d_in[4];
  float* out = (float*)d_out;

  unsigned short* wp = (unsigned short*)d_ws;  // 256 frags * 1KB = 256KB

  pack_w<<<64, 256, 0, stream>>>(W1, W2, wp);
  node_rk4<<<256, 512, 0, stream>>>(x0, b1, b2, wp, out);
}